// Round 9
// baseline (70.874 us; speedup 1.0000x reference)
//
#include <hip/hip_runtime.h>
#include <stdint.h>

typedef short v8s __attribute__((ext_vector_type(8)));
typedef float v4f __attribute__((ext_vector_type(4)));
typedef unsigned int u32;

#define CIN   320
#define COUT  320
#define HH    64
#define WW    64
#define BN    80
#define NT    10
#define WLB   15360      // one weight kh-slice in LDS: 3kw * 4cig * 80co * 16B
#define WKHB  61440      // bytes per (t,kh) slice in w_deq2: 3*4*320*16

__device__ __forceinline__ float hf8_decode_f(int b) {
    int e = (b >> 3) & 15;
    int m = b & 7;
    float v = ldexpf((float)(e ? (8 + m) : m), e ? (e - 17) : -16);
    return ((b >> 7) & 1) ? -v : v;
}

__device__ __forceinline__ u32 cvt_pk_bf16(float lo, float hi) {
    u32 r;
    asm("v_cvt_pk_bf16_f32 %0, %1, %2" : "=v"(r) : "v"(lo), "v"(hi));
    return r;
}

__device__ __forceinline__ void gload16(const void* g, void* l) {
    __builtin_amdgcn_global_load_lds(
        (const __attribute__((address_space(1))) u32*)(uintptr_t)g,
        (__attribute__((address_space(3))) u32*)(uintptr_t)l, 16, 0, 0);
}

// w_bits [Cout][Cin][3][3] -> w_deq2 [t(10)][kh(3)][kw(3)][cig(4)][co(320)][e(8)] bf16
__global__ void dequant_kernel(const int* __restrict__ w_bits,
                               const int* __restrict__ b_bits,
                               unsigned short* __restrict__ w_deq2,
                               float* __restrict__ b_deq) {
    int o  = blockIdx.x * 256 + threadIdx.x;   // 921600 = 3600*256
    int e  = o & 7;
    int c2 = o >> 3;
    int co = c2 % COUT;
    int c3 = c2 / COUT;
    int cig = c3 & 3;
    int c4 = c3 >> 2;
    int kw = c4 % 3;
    int c5 = c4 / 3;
    int kh = c5 % 3;
    int t  = c5 / 3;
    int ci = t * 32 + cig * 8 + e;
    float v = hf8_decode_f(w_bits[(co * CIN + ci) * 9 + kh * 3 + kw] & 0xFF);
    w_deq2[o] = (unsigned short)(__float_as_uint(v) >> 16);   // exact in bf16
    if (o < COUT) b_deq[o] = hf8_decode_f(b_bits[o] & 0xFF);
}

// ===== conv: 256 thr / 4 waves, 2 blocks/CU, kh-phase weight pipeline,
//       fused x staging with an EXCLUSIVE write phase (provably race-free) =====
__global__ __launch_bounds__(256, 2) void conv_phase_kernel(
        const float* __restrict__ x,
        const unsigned short* __restrict__ w_deq2,
        const float* __restrict__ b_deq,
        float* __restrict__ out) {
    __shared__ __align__(16) unsigned short xs[6 * 66 * 32];   // 25,344 B (single buffer)
    __shared__ __align__(16) unsigned short wl[2 * WLB / 2];   // 30,720 B (total 56,064)

    const int tid  = threadIdx.x;
    const int bid  = blockIdx.x;
    const int cob  = bid >> 7;        // 4 cobs; blocks sharing x (d=128, 128%8==0) on one XCD
    const int mb   = bid & 127;       // 8 img x 16 rowgroups
    const int n    = mb >> 4;
    const int h0   = (mb & 15) << 2;  // 4 output rows per block
    const int wave = tid >> 6;        // wave owns output row h0+wave
    const int lane = tid & 63;
    const int lhi  = lane >> 4;
    const int llo  = lane & 15;
    const int ciL2 = tid & 15;        // ci pair index (ci = 2*ciL2 in slab)
    const int seg  = tid >> 4;        // 4-wide w segment (0..15)

    // zero halo cols (xs col 0 and 65), once; rows at image edges stay zero via cvtWriteX
    if (tid < 192) {
        int row = tid >> 5, rem = tid & 31;
        int side = rem >> 4, e = rem & 15;
        *(u32*)((char*)xs + row * 4224 + side * 4160 + e * 4) = 0;
    }

    // per-lane constant weight gload offsets (chunk c = (wave*4+ii)*64 + lane)
    int woffW[4];
    #pragma unroll
    for (int ii = 0; ii < 4; ++ii) {
        int i = wave * 4 + ii;
        int c = i * 64 + lane;
        int q = c / BN;                        // kw*4+cig
        int co = c - q * BN;
        woffW[ii] = (q * COUT + cob * BN + co) << 4;
    }

    v4f acc[4][5];
    #pragma unroll
    for (int i = 0; i < 4; ++i)
        #pragma unroll
        for (int j = 0; j < 5; ++j)
            acc[i][j] = (v4f){0.f, 0.f, 0.f, 0.f};

    float4 xa[6], xbv[6];
    const float* xpl = x + ((size_t)(n * CIN) + 2 * ciL2) * (HH * WW);

    auto issueW = [&](int t_, int kh_, int wb) {
        const char* base = (const char*)w_deq2 + (size_t)(t_ * 3 + kh_) * WKHB;
        char* dst = (char*)wl + wb * WLB + wave * 4096;
        #pragma unroll
        for (int ii = 0; ii < 4; ++ii) {
            if (wave * 4 + ii < 15)
                gload16(base + woffW[ii], dst + ii * 1024);
        }
    };
    auto loadX = [&](int tt) {
        const float* xp0 = xpl + (size_t)(tt * 32) * (HH * WW);
        const float* xp1 = xp0 + HH * WW;
        #pragma unroll
        for (int r = 0; r < 6; ++r) {
            int gh = h0 - 1 + r;
            if (gh >= 0 && gh < HH) {
                xa[r]  = *(const float4*)(xp0 + gh * WW + seg * 4);
                xbv[r] = *(const float4*)(xp1 + gh * WW + seg * 4);
            } else {
                xa[r]  = make_float4(0.f, 0.f, 0.f, 0.f);
                xbv[r] = make_float4(0.f, 0.f, 0.f, 0.f);
            }
        }
    };
    auto cvtWriteX = [&]() {
        #pragma unroll
        for (int r = 0; r < 6; ++r) {
            u32 p0 = cvt_pk_bf16(xa[r].x, xbv[r].x);
            u32 p1 = cvt_pk_bf16(xa[r].y, xbv[r].y);
            u32 p2 = cvt_pk_bf16(xa[r].z, xbv[r].z);
            u32 p3 = cvt_pk_bf16(xa[r].w, xbv[r].w);
            char* c0 = (char*)xs + r * 4224 + (1 + seg * 4) * 64 + ciL2 * 4;
            *(u32*)(c0)       = p0;
            *(u32*)(c0 + 64)  = p1;
            *(u32*)(c0 + 128) = p2;
            *(u32*)(c0 + 192) = p3;
        }
    };
    auto computeKh = [&](int kh, int wb) {
        const char* xp = (const char*)xs + (wave + kh) * 4224;
        const unsigned short* wp = wl + wb * (WLB / 2);
        __builtin_amdgcn_s_setprio(1);
        #pragma unroll
        for (int kw = 0; kw < 3; ++kw) {
            v8s bfr[5];
            #pragma unroll
            for (int nr = 0; nr < 5; ++nr)
                bfr[nr] = *(const v8s*)&wp[((kw * 4 + lhi) * BN + nr * 16 + llo) * 8];
            #pragma unroll
            for (int mr = 0; mr < 4; ++mr) {
                v8s afr = *(const v8s*)(xp + (mr * 16 + llo + kw) * 64 + lhi * 16);
                #pragma unroll
                for (int nr = 0; nr < 5; ++nr)
                    acc[mr][nr] = __builtin_amdgcn_mfma_f32_16x16x32_bf16(
                        afr, bfr[nr], acc[mr][nr], 0, 0, 0);
            }
        }
        __builtin_amdgcn_s_setprio(0);
    };

    // prologue: weights(t0,kh0) -> wl[0]; x tile 0 -> regs -> xs (pre-barrier, exclusive)
    issueW(0, 0, 0);
    loadX(0);
    cvtWriteX();                 // vmcnt auto-wait at first register use

    for (int t = 0; t < NT; ++t) {
        const int p = t & 1;
        // ---- phase kh0: reads wl[p], xs ----
        __syncthreads();                        // A: w(t,kh0) drained; xs writes visible
        issueW(t, 1, p ^ 1);
        computeKh(0, p);
        // ---- phase kh1: reads wl[p^1] ----
        __syncthreads();                        // B: w(t,kh1) drained; kh0 reads of wl[p] done
        issueW(t, 2, p);
        if (t + 1 < NT) loadX(t + 1);           // f32 loads fly under kh1 MFMA
        computeKh(1, p ^ 1);
        // ---- phase kh2: reads wl[p] ----
        __syncthreads();                        // C: w(t,kh2) + x loads drained
        if (t + 1 < NT) issueW(t + 1, 0, p ^ 1);
        computeKh(2, p);
        // ---- exclusive x-write phase ----
        __syncthreads();                        // D: ALL xs reads of tile t complete
        if (t + 1 < NT) cvtWriteX();            // write tile t+1 (no concurrent readers)
    }

    // epilogue: bias + float4 stores
    const int h = h0 + wave;
    #pragma unroll
    for (int nr = 0; nr < 5; ++nr) {
        int co = cob * BN + nr * 16 + llo;      // D col = lane&15
        float bias = b_deq[co];
        float* op = out + ((size_t)(n * COUT + co) * HH + h) * WW;
        #pragma unroll
        for (int mr = 0; mr < 4; ++mr) {
            int wc = mr * 16 + lhi * 4;         // D row = (lane>>4)*4 + reg
            float4 o;
            o.x = acc[mr][nr][0] + bias;
            o.y = acc[mr][nr][1] + bias;
            o.z = acc[mr][nr][2] + bias;
            o.w = acc[mr][nr][3] + bias;
            *(float4*)(op + wc) = o;
        }
    }
}

extern "C" void kernel_launch(void* const* d_in, const int* in_sizes, int n_in,
                              void* d_out, int out_size, void* d_ws, size_t ws_size,
                              hipStream_t stream) {
    const float* x      = (const float*)d_in[0];
    const int*   w_bits = (const int*)d_in[1];
    const int*   b_bits = (const int*)d_in[2];
    float*       out    = (float*)d_out;

    unsigned short* w_deq2 = (unsigned short*)d_ws;                 // 1,843,200 B
    float*          b_deq  = (float*)((char*)d_ws + 1843200);

    dequant_kernel<<<3600, 256, 0, stream>>>(w_bits, b_bits, w_deq2, b_deq);
    // 4 cob x (8 img x 16 rowgroups) = 512 workgroups = 2 blocks/CU, zero tail
    conv_phase_kernel<<<512, 256, 0, stream>>>(x, w_deq2, b_deq, out);
}